// Round 1
// baseline (81.497 us; speedup 1.0000x reference)
//
#include <hip/hip_runtime.h>
#include <math.h>

#define BIG 1e30f

// QAM-16 gray-coded points, normalized by 1/sqrt(10). Compile-time derivable:
// real: sign=(i>>3)&1, mag=(i>>1)&1 -> +-{1,3}/sqrt(10)
// imag: sign=(i>>2)&1, mag=(i>>0)&1
__device__ __forceinline__ constexpr float QR(int i) {
    return ((((i >> 3) & 1) ? -1.0f : 1.0f) * ((((i >> 1) & 1) ? 3.0f : 1.0f)) *
            0.31622776601683794f);
}
__device__ __forceinline__ constexpr float QI(int i) {
    return ((((i >> 2) & 1) ? -1.0f : 1.0f) * (((i & 1) ? 3.0f : 1.0f)) *
            0.31622776601683794f);
}

// ---------------- Kernel 1: per-batch Cholesky + whitening -> G (3x3 herm), z (3) ---------------
__global__ __launch_bounds__(64, 1) void prep_kernel(
    const float* __restrict__ y_re, const float* __restrict__ y_im,
    const float* __restrict__ h_re, const float* __restrict__ h_im,
    const float* __restrict__ s_re, const float* __restrict__ s_im,
    float* __restrict__ ws, int B) {
    int b = blockIdx.x * blockDim.x + threadIdx.x;
    if (b >= B) return;
    const float* Sr = s_re + b * 64;
    const float* Si = s_im + b * 64;

    float Lr[8][8], Li[8][8], dinv[8];
    // Complex Cholesky, lower. L[i][j] = (S[i][j] - sum_k L[i][k]*conj(L[j][k])) / L[j][j]
#pragma unroll
    for (int i = 0; i < 8; ++i) {
#pragma unroll
        for (int j = 0; j < 8; ++j) {
            if (j < i) {
                float ar = Sr[i * 8 + j], ai = Si[i * 8 + j];
#pragma unroll
                for (int k = 0; k < 8; ++k) {
                    if (k < j) {
                        ar -= Lr[i][k] * Lr[j][k] + Li[i][k] * Li[j][k];
                        ai -= Li[i][k] * Lr[j][k] - Lr[i][k] * Li[j][k];
                    }
                }
                Lr[i][j] = ar * dinv[j];
                Li[i][j] = ai * dinv[j];
            }
        }
        float dd = Sr[i * 8 + i];
#pragma unroll
        for (int k = 0; k < 8; ++k) {
            if (k < i) dd -= Lr[i][k] * Lr[i][k] + Li[i][k] * Li[i][k];
        }
        float sq = sqrtf(dd);
        dinv[i] = 1.0f / sq;
    }

    // Forward solve L yw = y
    float ywr[8], ywi[8];
#pragma unroll
    for (int i = 0; i < 8; ++i) {
        float ar = y_re[b * 8 + i], ai = y_im[b * 8 + i];
#pragma unroll
        for (int k = 0; k < 8; ++k) {
            if (k < i) {
                ar -= Lr[i][k] * ywr[k] - Li[i][k] * ywi[k];
                ai -= Lr[i][k] * ywi[k] + Li[i][k] * ywr[k];
            }
        }
        ywr[i] = ar * dinv[i];
        ywi[i] = ai * dinv[i];
    }

    // Forward solve L hw = h (3 columns)
    float hwr[8][3], hwi[8][3];
#pragma unroll
    for (int c = 0; c < 3; ++c) {
#pragma unroll
        for (int i = 0; i < 8; ++i) {
            float ar = h_re[b * 24 + i * 3 + c], ai = h_im[b * 24 + i * 3 + c];
#pragma unroll
            for (int k = 0; k < 8; ++k) {
                if (k < i) {
                    ar -= Lr[i][k] * hwr[k][c] - Li[i][k] * hwi[k][c];
                    ai -= Lr[i][k] * hwi[k][c] + Li[i][k] * hwr[k][c];
                }
            }
            hwr[i][c] = ar * dinv[i];
            hwi[i][c] = ai * dinv[i];
        }
    }

    // G = hw^H hw (hermitian: 3 real diag + 3 complex offdiag), z = yw^H hw
    float g00 = 0, g11 = 0, g22 = 0;
    float g01r = 0, g01i = 0, g02r = 0, g02i = 0, g12r = 0, g12i = 0;
    float z0r = 0, z0i = 0, z1r = 0, z1i = 0, z2r = 0, z2i = 0;
#pragma unroll
    for (int m = 0; m < 8; ++m) {
        float a0r = hwr[m][0], a0i = hwi[m][0];
        float a1r = hwr[m][1], a1i = hwi[m][1];
        float a2r = hwr[m][2], a2i = hwi[m][2];
        g00 += a0r * a0r + a0i * a0i;
        g11 += a1r * a1r + a1i * a1i;
        g22 += a2r * a2r + a2i * a2i;
        g01r += a0r * a1r + a0i * a1i;
        g01i += a0r * a1i - a0i * a1r;
        g02r += a0r * a2r + a0i * a2i;
        g02i += a0r * a2i - a0i * a2r;
        g12r += a1r * a2r + a1i * a2i;
        g12i += a1r * a2i - a1i * a2r;
        float yr = ywr[m], yi = ywi[m];
        z0r += yr * a0r + yi * a0i;
        z0i += yr * a0i - yi * a0r;
        z1r += yr * a1r + yi * a1i;
        z1i += yr * a1i - yi * a1r;
        z2r += yr * a2r + yi * a2i;
        z2i += yr * a2i - yi * a2r;
    }
    float* o = ws + b * 16;
    o[0] = g00;  o[1] = g11;  o[2] = g22;
    o[3] = g01r; o[4] = g01i; o[5] = g02r; o[6] = g02i; o[7] = g12r; o[8] = g12i;
    o[9] = z0r;  o[10] = z0i; o[11] = z1r; o[12] = z1i; o[13] = z2r; o[14] = z2i;
    o[15] = 0.0f;
}

// ---------------- Kernel 2: candidate sweep + bitwise min reduction -> LLRs ----------------
// Block = batch. Thread tid = (i0<<4)|i1, loops i2 over 16 QAM points (unrolled).
// d(i0,i1,i2) = a0(i0)+a1(i1)+t01(i0,i1) + g22*|p2|^2 + cr*Re(p2) + ci*Im(p2)
// (yn term omitted: it is constant per batch and cancels in min0-min1)
__global__ __launch_bounds__(256, 1) void mld_search(const float* __restrict__ ws,
                                                     float* __restrict__ out) {
    int b = blockIdx.x;
    int tid = threadIdx.x;
    const float* w = ws + b * 16;
    float g00 = w[0], g11 = w[1], g22 = w[2];
    float g01r = w[3], g01i = w[4], g02r = w[5], g02i = w[6], g12r = w[7], g12i = w[8];
    float z0r = w[9], z0i = w[10], z1r = w[11], z1i = w[12], z2r = w[13], z2i = w[14];

    int i0 = tid >> 4, i1 = tid & 15;
    float p0r = QR(i0), p0i = QI(i0);
    float p1r = QR(i1), p1i = QI(i1);
    float n0 = p0r * p0r + p0i * p0i;
    float n1 = p1r * p1r + p1i * p1i;

    float a0 = g00 * n0 - 2.0f * (z0r * p0r - z0i * p0i);
    float a1 = g11 * n1 - 2.0f * (z1r * p1r - z1i * p1i);
    float crr = p0r * p1r + p0i * p1i;   // conj(p0)*p1
    float cri = p0r * p1i - p0i * p1r;
    float base = a0 + a1 + 2.0f * (g01r * crr - g01i * cri);
    float w0r = g02r * p0r + g02i * p0i;  // g02*conj(p0)
    float w0i = g02i * p0r - g02r * p0i;
    float w1r = g12r * p1r + g12i * p1i;  // g12*conj(p1)
    float w1i = g12i * p1r - g12r * p1i;
    float cr = 2.0f * (w0r + w1r - z2r);
    float ci = -2.0f * (w0i + w1i - z2i);

    // 8 accumulators: sym-2 bit n, value v -> m2[n*2+v]
    float m2[8];
#pragma unroll
    for (int j = 0; j < 8; ++j) m2[j] = BIG;
#pragma unroll
    for (int i2 = 0; i2 < 16; ++i2) {
        float pr = QR(i2), pi = QI(i2);
        float d = base + g22 * (pr * pr + pi * pi) + cr * pr + ci * pi;
        m2[0 + ((i2 >> 3) & 1)] = fminf(m2[0 + ((i2 >> 3) & 1)], d);
        m2[2 + ((i2 >> 2) & 1)] = fminf(m2[2 + ((i2 >> 2) & 1)], d);
        m2[4 + ((i2 >> 1) & 1)] = fminf(m2[4 + ((i2 >> 1) & 1)], d);
        m2[6 + (i2 & 1)]        = fminf(m2[6 + (i2 & 1)], d);
    }
    float tmin = fminf(m2[0], m2[1]);  // min over all i2 for this (i0,i1)

    __shared__ float s_tmin[256];
    __shared__ float s_r[32];   // [0..15] = min over i1 per i0 ; [16..31] = min over i0 per i1
    __shared__ float s_m2[32];  // per-wave m2 partials: [wave*8 + n*2 + v]
    s_tmin[tid] = tmin;

    // wave-level min reduction of the 8 sym-2 accumulators
#pragma unroll
    for (int j = 0; j < 8; ++j) {
        float v = m2[j];
#pragma unroll
        for (int mask = 1; mask < 64; mask <<= 1) v = fminf(v, __shfl_xor(v, mask, 64));
        m2[j] = v;
    }
    int wave = tid >> 6, lane = tid & 63;
    if (lane == 0) {
#pragma unroll
        for (int j = 0; j < 8; ++j) s_m2[wave * 8 + j] = m2[j];
    }
    __syncthreads();

    if (tid < 16) {
        float m = BIG;
#pragma unroll
        for (int j = 0; j < 16; ++j) m = fminf(m, s_tmin[tid * 16 + j]);
        s_r[tid] = m;  // min over i1 for i0=tid
    } else if (tid < 32) {
        int i1x = tid - 16;
        float m = BIG;
#pragma unroll
        for (int j = 0; j < 16; ++j) m = fminf(m, s_tmin[j * 16 + i1x]);
        s_r[16 + i1x] = m;  // min over i0 for i1=i1x
    }
    __syncthreads();

    if (tid < 12) {
        int k = tid >> 2, n = tid & 3, sh = 3 - n;
        float m0 = BIG, m1 = BIG;
        if (k < 2) {
            const float* r = s_r + k * 16;
#pragma unroll
            for (int j = 0; j < 16; ++j) {
                float v = r[j];
                if ((j >> sh) & 1) m1 = fminf(m1, v);
                else m0 = fminf(m0, v);
            }
        } else {
#pragma unroll
            for (int wv = 0; wv < 4; ++wv) {
                m0 = fminf(m0, s_m2[wv * 8 + n * 2 + 0]);
                m1 = fminf(m1, s_m2[wv * 8 + n * 2 + 1]);
            }
        }
        out[b * 12 + tid] = m0 - m1;  // llr = min0 - min1
    }
}

extern "C" void kernel_launch(void* const* d_in, const int* in_sizes, int n_in,
                              void* d_out, int out_size, void* d_ws, size_t ws_size,
                              hipStream_t stream) {
    const float* y_re = (const float*)d_in[0];
    const float* y_im = (const float*)d_in[1];
    const float* h_re = (const float*)d_in[2];
    const float* h_im = (const float*)d_in[3];
    const float* s_re = (const float*)d_in[4];
    const float* s_im = (const float*)d_in[5];
    int B = in_sizes[0] / 8;  // M = 8
    float* ws = (float*)d_ws; // needs B*16*4 = 256 KB

    prep_kernel<<<dim3((B + 63) / 64), dim3(64), 0, stream>>>(y_re, y_im, h_re, h_im,
                                                              s_re, s_im, ws, B);
    mld_search<<<dim3(B), dim3(256), 0, stream>>>(ws, (float*)d_out);
}